// Round 4
// baseline (202.041 us; speedup 1.0000x reference)
//
#include <hip/hip_runtime.h>
#include <cmath>

#define IMG_H 4096
#define IMG_W 4096
#define GX 8
#define GY 64
#define TCOLS 512            /* output cols per block */
#define WCOLS 128            /* output cols per wave (64 lanes x 2) */
#define R 64                 /* output rows per block */
#define NITER (R + 10)       /* 74 h-rows per strip */
#define GOUT ((NITER + 10) / 11)
#define SW 144               /* staged words per img per row per wave */
#define RWORDS (2*SW)        /* 288 words per wave-row (img1 then img2) */
#define NBUF 3               /* LDS ring depth: rows i, i+1, i+2 in flight */

struct GW { float w[11]; };

__device__ __forceinline__ int clampi(int v, int lo, int hi) {
  return v < lo ? lo : (v > hi ? hi : v);
}

// Round 4: resubmit of round 3 (container-level failure, no kernel evidence).
// Audit notes: LDS DMA worst-case ends at byte 13823/13824; all global srcs
// clamped+16B-aligned; vmcnt(4) accounting = 2 ops/row x 2 rows in flight;
// waitcnt cannot deadlock. Components HW-proven: global_load_lds w=16 (m97),
// counted vmcnt (m218).
// Design: global_load_lds + 3-deep wave-private LDS ring + counted vmcnt.
// Round-2 post-mortem: barrier-free waves got 144->108 us, VALUBusy 37->51%,
// but prefetch distance 1 leaves ~400 cy of HBM latency (~900 cy) exposed
// per ~500 cy iteration. Fix: DMA rows straight to LDS (no reg round-trip,
// no ds_write), issue row i+2 at iter i, wait s_waitcnt vmcnt(4) -- counted,
// never 0 in steady state (T3/T4). Slack = 2 iterations > HBM latency.
// Edges: clamp per-lane source col to a valid aligned 16B load, patch halo
// words in LDS after the wait (edge waves only). R=64: time tracks
// iteration count (round-1 lesson), 74 iters/64 rows beats 42/32.
// Lessons kept: LDS staging (direct-global = 2x loss), 4-channel algebra,
// no barriers in main loop, launch_bounds min-waves arg stays 2.
__global__ __launch_bounds__(256, 2) void ssim_sweep_kernel(
    const float* __restrict__ img1, const float* __restrict__ img2,
    float* __restrict__ partial, GW gw) {
  __shared__ __align__(16) float sbuf[4][NBUF][RWORDS];  // [wave][buf][word]

  const int tid  = threadIdx.x;
  const int wv   = tid >> 6;
  const int lane = tid & 63;
  const int bx = blockIdx.x, by = blockIdx.y;
  const int cw   = bx * TCOLS + wv * WCOLS;   // this wave's first output col
  const int row0 = by * R;
  const bool ledge = (cw == 0), redge = (cw + WCOLS == IMG_W);

  // DMA slot map: lane l writes bytes [16l,16l+16) of the row buffer.
  // words 0..143 = img1 cols [cw-8, cw+136); words 144..287 = img2 same.
  // call A: lanes 0..35 -> img1 slots 0..35; lanes 36..63 -> img2 slots 0..27
  // call B (8 lanes, base+1024B): lanes 0..7 -> img2 slots 28..35
  const int   jjA   = (lane < 36) ? lane : lane - 36;
  const float* baseA = (lane < 36) ? img1 : img2;
  const int   coA   = clampi(cw - 8 + 4 * jjA, 0, IMG_W - 4);      // 16B-aligned
  const int   coB   = clampi(cw - 8 + 4 * (lane + 28), 0, IMG_W - 4);

  float* swv = &sbuf[wv][0][0];

  auto stage = [&](int i) {
    const int b  = i % NBUF;
    const int gr = clampi(row0 - 5 + i, 0, IMG_H - 1);
    const long rb = (long)gr * IMG_W;
    float* dst = swv + b * RWORDS;
    __builtin_amdgcn_global_load_lds(
        (const __attribute__((address_space(1))) void*)(baseA + rb + coA),
        (__attribute__((address_space(3))) void*)dst, 16, 0, 0);
    if (lane < 8) {
      __builtin_amdgcn_global_load_lds(
          (const __attribute__((address_space(1))) void*)(img2 + rb + coB),
          (__attribute__((address_space(3))) void*)(dst + 256), 16, 0, 0);
    }
  };

  // ---- prologue: rows 0,1 in flight ----
  stage(0);
  stage(1);

  // ring: 4 channels {mu1, mu2, E[x^2+y^2], E[xy]} x 11 slots x 2 cols
  float acc[4][11][2];
  float sum = 0.f;
  const float C1 = 6.5025f, C2 = 58.5225f;
  const int base = 2 * lane + 2;  // first staged word of this lane's window

  for (int g = 0; g < GOUT; ++g) {
    #pragma unroll
    for (int p = 0; p < 11; ++p) {
      const int i = g * 11 + p;
      if (i < NITER) {
        // issue row i+2 into the buffer freed at iter i-1
        if (i + 2 < NITER) stage(i + 2);

        // counted wait: rows i+1 (2 ops) and i+2 (2 ops) stay in flight
        if (i + 2 < NITER) {
          asm volatile("s_waitcnt vmcnt(4)" ::: "memory");
        } else if (i + 1 < NITER) {
          asm volatile("s_waitcnt vmcnt(2)" ::: "memory");
        } else {
          asm volatile("s_waitcnt vmcnt(0)" ::: "memory");
        }
        __builtin_amdgcn_sched_barrier(0);

        float* buf = swv + (i % NBUF) * RWORDS;

        // replicate-pad patch (edge waves only; words outside valid image)
        if (ledge || redge) {
          if (lane < 16) {
            const int im = lane >> 3, l = lane & 7;
            const int srcw = im * SW + (ledge ? 8 : 135);
            const int dstw = im * SW + (ledge ? l : 136 + l);
            buf[dstw] = buf[srcw];
          }
        }

        // window: staged words [2lane+2, 2lane+16); used: [1..12]
        float wa[14], wb[14];
        #pragma unroll
        for (int m = 0; m < 7; ++m) {
          float2 fa = *reinterpret_cast<const float2*>(&buf[base + 2 * m]);
          float2 fb = *reinterpret_cast<const float2*>(&buf[SW + base + 2 * m]);
          wa[2 * m] = fa.x; wa[2 * m + 1] = fa.y;
          wb[2 * m] = fb.x; wb[2 * m + 1] = fb.y;
        }

        // fused 4-channel horizontal conv, element-centric, 2 cols
        float h[4][2];
        #pragma unroll
        for (int ch = 0; ch < 4; ++ch) { h[ch][0] = 0.f; h[ch][1] = 0.f; }
        #pragma unroll
        for (int e = 1; e <= 12; ++e) {
          const float a = wa[e], b = wb[e];
          const float sq = fmaf(b, b, a * a);   // x^2 + y^2
          const float ab = a * b;               // x*y
          if (e <= 11) {               // tap j = e-1 for col 0
            const float w0 = gw.w[e - 1];
            h[0][0] = fmaf(w0, a,  h[0][0]);
            h[1][0] = fmaf(w0, b,  h[1][0]);
            h[2][0] = fmaf(w0, sq, h[2][0]);
            h[3][0] = fmaf(w0, ab, h[3][0]);
          }
          if (e >= 2) {                // tap j = e-2 for col 1
            const float w1 = gw.w[e - 2];
            h[0][1] = fmaf(w1, a,  h[0][1]);
            h[1][1] = fmaf(w1, b,  h[1][1]);
            h[2][1] = fmaf(w1, sq, h[2][1]);
            h[3][1] = fmaf(w1, ab, h[3][1]);
          }
        }

        // scatter: input row i feeds outputs t=i-10+m (m=0..10),
        // slot (p+1+m)%11, weight w[10-m]; m=10 starts output t=i -> mul
        #pragma unroll
        for (int m = 0; m <= 10; ++m) {
          const int s = (p + 1 + m) % 11;
          const float wd = gw.w[10 - m];
          if (m == 10) {
            #pragma unroll
            for (int ch = 0; ch < 4; ++ch) {
              acc[ch][s][0] = wd * h[ch][0];
              acc[ch][s][1] = wd * h[ch][1];
            }
          } else {
            #pragma unroll
            for (int ch = 0; ch < 4; ++ch) {
              acc[ch][s][0] = fmaf(wd, h[ch][0], acc[ch][s][0]);
              acc[ch][s][1] = fmaf(wd, h[ch][1], acc[ch][s][1]);
            }
          }
        }

        // output row t=i-10 complete in slot (p+1)%11 -> SSIM + sum
        if (i >= 10) {
          const int cs = (p + 1) % 11;
          #pragma unroll
          for (int x = 0; x < 2; ++x) {
            float mu1 = acc[0][cs][x], mu2 = acc[1][cs][x];
            float s3  = acc[2][cs][x], s4  = acc[3][cs][x];
            float mu1s = mu1 * mu1, mu2s = mu2 * mu2, m12 = mu1 * mu2;
            float num = (2.f * m12 + C1) * (2.f * (s4 - m12) + C2);
            float den = (mu1s + mu2s + C1) * ((s3 - mu1s - mu2s) + C2);
            sum += num * __builtin_amdgcn_rcpf(den);
          }
        }
      }
    }
  }

  // ---- block reduction (single barrier, end of kernel) ----
  #pragma unroll
  for (int off = 32; off > 0; off >>= 1) sum += __shfl_down(sum, off);
  __shared__ float wsum[4];
  if (lane == 0) wsum[wv] = sum;
  __syncthreads();
  if (tid == 0)
    partial[by * GX + bx] = wsum[0] + wsum[1] + wsum[2] + wsum[3];
}

__global__ __launch_bounds__(256) void ssim_reduce_kernel(
    const float* __restrict__ partial, float* __restrict__ out) {
  int tid = threadIdx.x;
  // 512 partials (GX*GY)
  double s = (double)partial[tid] + (double)partial[tid + 256];
  #pragma unroll
  for (int off = 32; off > 0; off >>= 1) s += __shfl_down(s, off);
  __shared__ double ws[4];
  if ((tid & 63) == 0) ws[tid >> 6] = s;
  __syncthreads();
  if (tid == 0)
    out[0] = (float)((ws[0] + ws[1] + ws[2] + ws[3]) /
                     ((double)IMG_H * (double)IMG_W));
}

extern "C" void kernel_launch(void* const* d_in, const int* in_sizes, int n_in,
                              void* d_out, int out_size, void* d_ws, size_t ws_size,
                              hipStream_t stream) {
  const float* img1 = (const float*)d_in[0];
  const float* img2 = (const float*)d_in[1];
  float* partial = (float*)d_ws;
  float* out = (float*)d_out;

  GW gw;
  double g[11], s = 0.0;
  for (int i = 0; i < 11; ++i) {
    double x = i - 5.0;
    g[i] = exp(-(x * x) / (2.0 * 1.5 * 1.5));
    s += g[i];
  }
  for (int i = 0; i < 11; ++i) gw.w[i] = (float)(g[i] / s);

  dim3 grid(GX, GY);
  ssim_sweep_kernel<<<grid, 256, 0, stream>>>(img1, img2, partial, gw);
  ssim_reduce_kernel<<<1, 256, 0, stream>>>(partial, out);
}

// Round 5
// 201.039 us; speedup vs baseline: 1.0050x; 1.0050x over previous
//
#include <hip/hip_runtime.h>
#include <cmath>

#define IMG_H 4096
#define IMG_W 4096
#define GX 8
#define GY 64
#define TCOLS 512            /* output cols per block */
#define WCOLS 128            /* output cols per wave (64 lanes x 2) */
#define R 64                 /* output rows per block */
#define NITER (R + 10)       /* 74 h-rows per strip */
#define SW 144               /* staged words per img per row per wave */
#define RWORDS (2*SW)        /* 288 words per wave-row (img1 then img2) */
#define NBUF 3               /* LDS ring depth: rows i, i+1, i+2 in flight */

struct GW { float w[11]; };

__device__ __forceinline__ int clampi(int v, int lo, int hi) {
  return v < lo ? lo : (v > hi ? hi : v);
}

// Round 5: ROLLED main loop via shift-register accumulator.
// Round-4 post-mortem: per-wave-iter VALU is ~780 cy (consistent r2/r4) but
// wall is ~1600 cy/wave-iter and scales WITH resident waves (r2: 4 waves,
// T=6171; r4: 2 waves, T=3310) -> a per-CU serialized ~760 cy/wave-iter
// resource, not latency. LDS pipe ~25%, HBM 10%. Fetch demand pins at
// ~9 B/cy in BOTH rounds: the 11-phase unrolled body (~40 KB) thrashes the
// 32 KB L1I with phase-offset waves. Fix: kill the unroll. The %11 ring
// becomes a shift register where the shift folds into the accumulate:
//   A[k] = fmaf(w[10-k], h, A[k+1])  (in-place, k ascending), A[10] = w0*h
// Same FLOPs as the scatter, static indices, one ~3 KB loop body.
// Counted vmcnt now unconditional: tail stages are clamped re-reads into
// already-consumed ring slots (harmless), so no branchy epilogue.
// Lessons kept: wave-private LDS + no barriers (r2), global_load_lds w=16
// 3-deep ring + vmcnt(4) (r4, correctness HW-proven), R=64 (time tracks
// iterations, r1), 4-channel algebra, launch_bounds min-waves = 2.
__global__ __launch_bounds__(256, 2) void ssim_sweep_kernel(
    const float* __restrict__ img1, const float* __restrict__ img2,
    float* __restrict__ partial, GW gw) {
  __shared__ __align__(16) float sbuf[4][NBUF][RWORDS];  // [wave][buf][word]

  const int tid  = threadIdx.x;
  const int wv   = tid >> 6;
  const int lane = tid & 63;
  const int bx = blockIdx.x, by = blockIdx.y;
  const int cw   = bx * TCOLS + wv * WCOLS;   // this wave's first output col
  const int row0 = by * R;
  const bool ledge = (cw == 0), redge = (cw + WCOLS == IMG_W);

  // DMA slot map: lane l writes bytes [16l,16l+16) of the row buffer.
  // words 0..143 = img1 cols [cw-8, cw+136); words 144..287 = img2 same.
  // call A: lanes 0..35 -> img1 slots 0..35; lanes 36..63 -> img2 slots 0..27
  // call B (8 lanes, base+1024B): lanes 0..7 -> img2 slots 28..35
  const int   jjA   = (lane < 36) ? lane : lane - 36;
  const float* baseA = (lane < 36) ? img1 : img2;
  const int   coA   = clampi(cw - 8 + 4 * jjA, 0, IMG_W - 4);      // 16B-aligned
  const int   coB   = clampi(cw - 8 + 4 * (lane + 28), 0, IMG_W - 4);

  float* swv = &sbuf[wv][0][0];

  auto stage = [&](int slot, int i) {
    const int gr = clampi(row0 - 5 + i, 0, IMG_H - 1);
    const long rb = (long)gr * IMG_W;
    float* dst = swv + slot * RWORDS;
    __builtin_amdgcn_global_load_lds(
        (const __attribute__((address_space(1))) void*)(baseA + rb + coA),
        (__attribute__((address_space(3))) void*)dst, 16, 0, 0);
    if (lane < 8) {
      __builtin_amdgcn_global_load_lds(
          (const __attribute__((address_space(1))) void*)(img2 + rb + coB),
          (__attribute__((address_space(3))) void*)(dst + 256), 16, 0, 0);
    }
  };

  // ---- prologue: rows 0,1 in flight ----
  stage(0, 0);
  stage(1, 1);

  // shift-register accumulator: A[ch][k][col], k=0..10.
  // After the update at iter i, A[..][0][..] = completed output row i-10.
  float A[4][11][2];
  float sum = 0.f;
  const float C1 = 6.5025f, C2 = 58.5225f;
  const int base = 2 * lane + 2;  // first staged word of this lane's window

  int cur = 0;  // ring slot holding row i

  #pragma unroll 1
  for (int i = 0; i < NITER; ++i) {
    // issue row i+2 into the slot freed at iter i-1 ((cur+2)%3)
    const int pre = (cur == 0) ? 2 : cur - 1;
    stage(pre, i + 2);

    // counted wait: rows i+1, i+2 (2 ops each) stay in flight
    asm volatile("s_waitcnt vmcnt(4)" ::: "memory");
    __builtin_amdgcn_sched_barrier(0);

    float* buf = swv + cur * RWORDS;
    cur = (cur == 2) ? 0 : cur + 1;

    // replicate-pad patch (edge waves only; words outside valid image)
    if (ledge || redge) {
      if (lane < 16) {
        const int im = lane >> 3, l = lane & 7;
        const int srcw = im * SW + (ledge ? 8 : 135);
        const int dstw = im * SW + (ledge ? l : 136 + l);
        buf[dstw] = buf[srcw];
      }
    }

    // window: staged words [2lane+2, 2lane+16); used: [1..12]
    float wa[14], wb[14];
    #pragma unroll
    for (int m = 0; m < 7; ++m) {
      float2 fa = *reinterpret_cast<const float2*>(&buf[base + 2 * m]);
      float2 fb = *reinterpret_cast<const float2*>(&buf[SW + base + 2 * m]);
      wa[2 * m] = fa.x; wa[2 * m + 1] = fa.y;
      wb[2 * m] = fb.x; wb[2 * m + 1] = fb.y;
    }

    // fused 4-channel horizontal conv, element-centric, 2 cols
    float h[4][2];
    #pragma unroll
    for (int ch = 0; ch < 4; ++ch) { h[ch][0] = 0.f; h[ch][1] = 0.f; }
    #pragma unroll
    for (int e = 1; e <= 12; ++e) {
      const float a = wa[e], b = wb[e];
      const float sq = fmaf(b, b, a * a);   // x^2 + y^2
      const float ab = a * b;               // x*y
      if (e <= 11) {               // tap j = e-1 for col 0
        const float w0 = gw.w[e - 1];
        h[0][0] = fmaf(w0, a,  h[0][0]);
        h[1][0] = fmaf(w0, b,  h[1][0]);
        h[2][0] = fmaf(w0, sq, h[2][0]);
        h[3][0] = fmaf(w0, ab, h[3][0]);
      }
      if (e >= 2) {                // tap j = e-2 for col 1
        const float w1 = gw.w[e - 2];
        h[0][1] = fmaf(w1, a,  h[0][1]);
        h[1][1] = fmaf(w1, b,  h[1][1]);
        h[2][1] = fmaf(w1, sq, h[2][1]);
        h[3][1] = fmaf(w1, ab, h[3][1]);
      }
    }

    // shift-fma vertical accumulate: A[k] = w[10-k]*h + A[k+1] (in place,
    // ascending k reads old A[k+1] before it is overwritten); A[10] = w0*h.
    #pragma unroll
    for (int ch = 0; ch < 4; ++ch) {
      #pragma unroll
      for (int x = 0; x < 2; ++x) {
        const float hv = h[ch][x];
        #pragma unroll
        for (int k = 0; k < 10; ++k)
          A[ch][k][x] = fmaf(gw.w[10 - k], hv, A[ch][k + 1][x]);
        A[ch][10][x] = gw.w[0] * hv;
      }
    }

    // output row i-10 complete in A[..][0][..] -> SSIM + sum
    if (i >= 10) {
      #pragma unroll
      for (int x = 0; x < 2; ++x) {
        float mu1 = A[0][0][x], mu2 = A[1][0][x];
        float s3  = A[2][0][x], s4  = A[3][0][x];
        float mu1s = mu1 * mu1, mu2s = mu2 * mu2, m12 = mu1 * mu2;
        float num = (2.f * m12 + C1) * (2.f * (s4 - m12) + C2);
        float den = (mu1s + mu2s + C1) * ((s3 - mu1s - mu2s) + C2);
        sum += num * __builtin_amdgcn_rcpf(den);
      }
    }
  }

  // ---- block reduction (single barrier, end of kernel) ----
  #pragma unroll
  for (int off = 32; off > 0; off >>= 1) sum += __shfl_down(sum, off);
  __shared__ float wsum[4];
  if (lane == 0) wsum[wv] = sum;
  __syncthreads();
  if (tid == 0)
    partial[by * GX + bx] = wsum[0] + wsum[1] + wsum[2] + wsum[3];
}

__global__ __launch_bounds__(256) void ssim_reduce_kernel(
    const float* __restrict__ partial, float* __restrict__ out) {
  int tid = threadIdx.x;
  // 512 partials (GX*GY)
  double s = (double)partial[tid] + (double)partial[tid + 256];
  #pragma unroll
  for (int off = 32; off > 0; off >>= 1) s += __shfl_down(s, off);
  __shared__ double ws[4];
  if ((tid & 63) == 0) ws[tid >> 6] = s;
  __syncthreads();
  if (tid == 0)
    out[0] = (float)((ws[0] + ws[1] + ws[2] + ws[3]) /
                     ((double)IMG_H * (double)IMG_W));
}

extern "C" void kernel_launch(void* const* d_in, const int* in_sizes, int n_in,
                              void* d_out, int out_size, void* d_ws, size_t ws_size,
                              hipStream_t stream) {
  const float* img1 = (const float*)d_in[0];
  const float* img2 = (const float*)d_in[1];
  float* partial = (float*)d_ws;
  float* out = (float*)d_out;

  GW gw;
  double g[11], s = 0.0;
  for (int i = 0; i < 11; ++i) {
    double x = i - 5.0;
    g[i] = exp(-(x * x) / (2.0 * 1.5 * 1.5));
    s += g[i];
  }
  for (int i = 0; i < 11; ++i) gw.w[i] = (float)(g[i] / s);

  dim3 grid(GX, GY);
  ssim_sweep_kernel<<<grid, 256, 0, stream>>>(img1, img2, partial, gw);
  ssim_reduce_kernel<<<1, 256, 0, stream>>>(partial, out);
}

// Round 7
// 187.522 us; speedup vs baseline: 1.0774x; 1.0721x over previous
//
#include <hip/hip_runtime.h>
#include <cmath>

#define IMG_H 4096
#define IMG_W 4096
#define GX 16
#define GY 64
#define TCOLS 256            /* output cols per block (4 waves x 64) */
#define WCOLS 64             /* output cols per wave (1 col per lane) */
#define R 64                 /* output rows per block */
#define NITER (R + 10)       /* 74 h-rows per strip */
#define SW 80                /* staged words per img per row per wave: [cw-8, cw+72) */
#define RWORDS (2*SW)        /* 160 words per wave-row (img1 then img2) */
#define NBUF 3               /* LDS ring depth */

struct GW { float w[11]; };

__device__ __forceinline__ int clampi(int v, int lo, int hi) {
  return v < lo ? lo : (v > hi ? hi : v);
}

// Round 7: VERBATIM resubmit of round 6 (container failed twice; round 3's
// identical failure mode cleared on verbatim resubmit in round 4 -> infra).
// Audit: DMA writes exactly RWORDS*4 bytes/slot (lanes 0..39, masked lanes
// don't write); sources clamped to [0,4092] 16B-aligned; edge patch covers
// words 0..7 / 72..79; vmcnt(2) = 1 op/row x 2 rows in flight.
//
// Round 6: occupancy unlock via 1-col-per-lane + VGPR <= 85.
// Ledger r0-r5: occupancy pinned at ~20% (2 waves/SIMD) in EVERY config
// (grid 512 vs 1024, barriers or not, DMA or not, rolled or not); per-CU
// throughput pinned ~400 cy/wave-iter. Prior session: launch_bounds(256,4)
// forced a 64-VGPR cap => backend's per-SIMD allocatable pool = 4x64 = 256
// VGPRs (not 512). Under pool=256, VGPR 96-128 => floor(256/v) = 2
// waves/SIMD exactly -- matches all six measurements. The 2-col ring
// (A[4][11][2]+h = 96 regs irreducible) self-capped occupancy all along.
// Fix: 1 col/lane => A[4][11] = 44 regs, natural pressure ~70;
// launch_bounds(256,3) caps at 85 (no spill risk; forcing 64 would spill).
// Grid 16x64 = 1024 blocks so 3+ workgroups/CU can be resident.
// Cost: 2x wave-iters, but per-iter VALU halves and LDS/iter drops 14->12.
// Lessons kept: wave-private LDS, no main-loop barriers (r2), w=16
// global_load_lds ring + counted vmcnt (r4), R=64 halo efficiency (r1),
// 4-channel algebra, rolled loop (r5: smaller is never worse).
__global__ __launch_bounds__(256, 3) void ssim_sweep_kernel(
    const float* __restrict__ img1, const float* __restrict__ img2,
    float* __restrict__ partial, GW gw) {
  __shared__ __align__(16) float sbuf[4][NBUF][RWORDS];  // [wave][buf][word]

  const int tid  = threadIdx.x;
  const int wv   = tid >> 6;
  const int lane = tid & 63;
  const int bx = blockIdx.x, by = blockIdx.y;
  const int cw   = bx * TCOLS + wv * WCOLS;   // this wave's first output col
  const int row0 = by * R;
  const bool ledge = (cw == 0), redge = (cw + WCOLS == IMG_W);

  // DMA map: one call, lanes 0..39 active; HW writes LDS base + 16*laneid.
  // lanes 0..19  -> img1 words 0..79   (cols [cw-8, cw+72))
  // lanes 20..39 -> img2 words 80..159 (16*20 = 320 B = word 80)
  const float* srcp = (lane < 20) ? img1 : img2;
  const int    co   = clampi(cw - 8 + 4 * ((lane < 20) ? lane : lane - 20),
                             0, IMG_W - 4);   // 16B-aligned (cw%64==0)

  float* swv = &sbuf[wv][0][0];

  auto stage = [&](int slot, int i) {
    const int gr = clampi(row0 - 5 + i, 0, IMG_H - 1);
    const long rb = (long)gr * IMG_W;
    float* dst = swv + slot * RWORDS;
    if (lane < 40) {
      __builtin_amdgcn_global_load_lds(
          (const __attribute__((address_space(1))) void*)(srcp + rb + co),
          (__attribute__((address_space(3))) void*)dst, 16, 0, 0);
    }
  };

  // ---- prologue: rows 0,1 in flight ----
  stage(0, 0);
  stage(1, 1);

  // shift-register accumulator: A[ch][k], k=0..10; 1 col per lane.
  float A[4][11];
  float sum = 0.f;
  const float C1 = 6.5025f, C2 = 58.5225f;
  const int wl = lane + 3;   // first window word (col cw+lane, taps -5..+5)

  int cur = 0;  // ring slot holding row i

  #pragma unroll 1
  for (int i = 0; i < NITER; ++i) {
    // issue row i+2 into the slot freed at iter i-1 (clamped re-read at tail)
    const int pre = (cur == 0) ? 2 : cur - 1;
    stage(pre, i + 2);

    // counted wait: rows i+1, i+2 (1 op each) stay in flight
    asm volatile("s_waitcnt vmcnt(2)" ::: "memory");
    __builtin_amdgcn_sched_barrier(0);

    float* buf = swv + cur * RWORDS;
    cur = (cur == 2) ? 0 : cur + 1;

    // replicate-pad patch (edge waves only)
    if (ledge || redge) {
      if (lane < 16) {
        const int im = lane >> 3, l = lane & 7;
        const int srcw = im * SW + (ledge ? 8 : 71);
        const int dstw = im * SW + (ledge ? l : 72 + l);
        buf[dstw] = buf[srcw];
      }
    }

    // fused 4-channel horizontal conv, 1 col, streaming taps
    float h0 = 0.f, h1 = 0.f, h2 = 0.f, h3 = 0.f;
    #pragma unroll
    for (int j = 0; j <= 10; ++j) {
      const float a = buf[wl + j];
      const float b = buf[SW + wl + j];
      const float w = gw.w[j];
      const float sq = fmaf(b, b, a * a);   // x^2 + y^2
      const float ab = a * b;               // x*y
      h0 = fmaf(w, a,  h0);
      h1 = fmaf(w, b,  h1);
      h2 = fmaf(w, sq, h2);
      h3 = fmaf(w, ab, h3);
    }

    // shift-fma vertical accumulate: A[k] = w[10-k]*h + A[k+1] (in place,
    // ascending k reads old A[k+1] before overwrite); A[10] = w[0]*h.
    #pragma unroll
    for (int k = 0; k < 10; ++k) {
      A[0][k] = fmaf(gw.w[10 - k], h0, A[0][k + 1]);
      A[1][k] = fmaf(gw.w[10 - k], h1, A[1][k + 1]);
      A[2][k] = fmaf(gw.w[10 - k], h2, A[2][k + 1]);
      A[3][k] = fmaf(gw.w[10 - k], h3, A[3][k + 1]);
    }
    A[0][10] = gw.w[0] * h0;
    A[1][10] = gw.w[0] * h1;
    A[2][10] = gw.w[0] * h2;
    A[3][10] = gw.w[0] * h3;

    // output row i-10 complete in A[..][0] -> SSIM + sum
    if (i >= 10) {
      const float mu1 = A[0][0], mu2 = A[1][0];
      const float s3  = A[2][0], s4  = A[3][0];
      const float mu1s = mu1 * mu1, mu2s = mu2 * mu2, m12 = mu1 * mu2;
      const float num = (2.f * m12 + C1) * (2.f * (s4 - m12) + C2);
      const float den = (mu1s + mu2s + C1) * ((s3 - mu1s - mu2s) + C2);
      sum += num * __builtin_amdgcn_rcpf(den);
    }
  }

  // ---- block reduction (single barrier, end of kernel) ----
  #pragma unroll
  for (int off = 32; off > 0; off >>= 1) sum += __shfl_down(sum, off);
  __shared__ float wsum[4];
  if (lane == 0) wsum[wv] = sum;
  __syncthreads();
  if (tid == 0)
    partial[by * GX + bx] = wsum[0] + wsum[1] + wsum[2] + wsum[3];
}

__global__ __launch_bounds__(256) void ssim_reduce_kernel(
    const float* __restrict__ partial, float* __restrict__ out) {
  int tid = threadIdx.x;
  // 1024 partials (GX*GY)
  double s = (double)partial[tid] + (double)partial[tid + 256] +
             (double)partial[tid + 512] + (double)partial[tid + 768];
  #pragma unroll
  for (int off = 32; off > 0; off >>= 1) s += __shfl_down(s, off);
  __shared__ double ws[4];
  if ((tid & 63) == 0) ws[tid >> 6] = s;
  __syncthreads();
  if (tid == 0)
    out[0] = (float)((ws[0] + ws[1] + ws[2] + ws[3]) /
                     ((double)IMG_H * (double)IMG_W));
}

extern "C" void kernel_launch(void* const* d_in, const int* in_sizes, int n_in,
                              void* d_out, int out_size, void* d_ws, size_t ws_size,
                              hipStream_t stream) {
  const float* img1 = (const float*)d_in[0];
  const float* img2 = (const float*)d_in[1];
  float* partial = (float*)d_ws;
  float* out = (float*)d_out;

  GW gw;
  double g[11], s = 0.0;
  for (int i = 0; i < 11; ++i) {
    double x = i - 5.0;
    g[i] = exp(-(x * x) / (2.0 * 1.5 * 1.5));
    s += g[i];
  }
  for (int i = 0; i < 11; ++i) gw.w[i] = (float)(g[i] / s);

  dim3 grid(GX, GY);
  ssim_sweep_kernel<<<grid, 256, 0, stream>>>(img1, img2, partial, gw);
  ssim_reduce_kernel<<<1, 256, 0, stream>>>(partial, out);
}

// Round 8
// 185.656 us; speedup vs baseline: 1.0883x; 1.0100x over previous
//
#include <hip/hip_runtime.h>
#include <cmath>

#define IMG_H 4096
#define IMG_W 4096
#define GX 32
#define GY 64
#define TCOLS 128            /* output cols per block (2 waves x 64) */
#define WCOLS 64             /* output cols per wave (1 col per lane) */
#define R 64                 /* output rows per block */
#define NITER (R + 10)       /* 74 h-rows per strip */
#define SW 80                /* staged words per img per row per wave: [cw-8, cw+72) */
#define RWORDS (2*SW)        /* 160 words per wave-row (img1 then img2) */
#define NBUF 3               /* LDS ring depth */
#define NWV 2                /* waves per block */

struct GW { float w[11]; };

__device__ __forceinline__ int clampi(int v, int lo, int hi) {
  return v < lo ? lo : (v > hi ? hi : v);
}

// Round 8: occupancy fill via 2-wave blocks + 2048-block grid.
// Round-7 post-mortem: pool theory CONFIRMED. VGPR 40, occupancy 20->30%,
// VALUBusy 76%, conflicts 0, sweep 95.6 us. VALU-issue time = 73 us; the
// 24% idle is unhidden latency at ~2.4 eff waves/SIMD. Grid supplied only
// 4 blocks/CU in 4-wave quanta -> ramp/tail keeps residency below the 16
// waves/CU the VGPRs now permit (256-pool / 40 = 6 waves/SIMD possible).
// Fix: 128-thread blocks, GX=32 (TCOLS 128), 2048 blocks = 8 blocks/CU x
// 2 waves = 4 waves/SIMD steady state, finer dispatch granularity.
// R=64 kept: halo efficiency (r1), wave-iter count unchanged vs r7.
// launch_bounds(128,4): VGPR cap 64 >= 40 observed, no spill.
// Lessons kept: wave-private LDS, no main-loop barriers (r2), w=16
// global_load_lds 3-ring + counted vmcnt(2) (r4/r7), rolled loop + shift
// register (r5), 1 col/lane A[4][11] (r7), 4-channel algebra.
__global__ __launch_bounds__(128, 4) void ssim_sweep_kernel(
    const float* __restrict__ img1, const float* __restrict__ img2,
    float* __restrict__ partial, GW gw) {
  __shared__ __align__(16) float sbuf[NWV][NBUF][RWORDS];  // [wave][buf][word]

  const int tid  = threadIdx.x;
  const int wv   = tid >> 6;
  const int lane = tid & 63;
  const int bx = blockIdx.x, by = blockIdx.y;
  const int cw   = bx * TCOLS + wv * WCOLS;   // this wave's first output col
  const int row0 = by * R;
  const bool ledge = (cw == 0), redge = (cw + WCOLS == IMG_W);

  // DMA map: one call, lanes 0..39 active; HW writes LDS base + 16*laneid.
  // lanes 0..19  -> img1 words 0..79   (cols [cw-8, cw+72))
  // lanes 20..39 -> img2 words 80..159 (16*20 = 320 B = word 80)
  const float* srcp = (lane < 20) ? img1 : img2;
  const int    co   = clampi(cw - 8 + 4 * ((lane < 20) ? lane : lane - 20),
                             0, IMG_W - 4);   // 16B-aligned (cw%64==0)

  float* swv = &sbuf[wv][0][0];

  auto stage = [&](int slot, int i) {
    const int gr = clampi(row0 - 5 + i, 0, IMG_H - 1);
    const long rb = (long)gr * IMG_W;
    float* dst = swv + slot * RWORDS;
    if (lane < 40) {
      __builtin_amdgcn_global_load_lds(
          (const __attribute__((address_space(1))) void*)(srcp + rb + co),
          (__attribute__((address_space(3))) void*)dst, 16, 0, 0);
    }
  };

  // ---- prologue: rows 0,1 in flight ----
  stage(0, 0);
  stage(1, 1);

  // shift-register accumulator: A[ch][k], k=0..10; 1 col per lane.
  float A[4][11];
  float sum = 0.f;
  const float C1 = 6.5025f, C2 = 58.5225f;
  const int wl = lane + 3;   // first window word (col cw+lane, taps -5..+5)

  int cur = 0;  // ring slot holding row i

  #pragma unroll 1
  for (int i = 0; i < NITER; ++i) {
    // issue row i+2 into the slot freed at iter i-1 (clamped re-read at tail)
    const int pre = (cur == 0) ? 2 : cur - 1;
    stage(pre, i + 2);

    // counted wait: rows i+1, i+2 (1 op each) stay in flight
    asm volatile("s_waitcnt vmcnt(2)" ::: "memory");
    __builtin_amdgcn_sched_barrier(0);

    float* buf = swv + cur * RWORDS;
    cur = (cur == 2) ? 0 : cur + 1;

    // replicate-pad patch (edge waves only)
    if (ledge || redge) {
      if (lane < 16) {
        const int im = lane >> 3, l = lane & 7;
        const int srcw = im * SW + (ledge ? 8 : 71);
        const int dstw = im * SW + (ledge ? l : 72 + l);
        buf[dstw] = buf[srcw];
      }
    }

    // fused 4-channel horizontal conv, 1 col, streaming taps
    float h0 = 0.f, h1 = 0.f, h2 = 0.f, h3 = 0.f;
    #pragma unroll
    for (int j = 0; j <= 10; ++j) {
      const float a = buf[wl + j];
      const float b = buf[SW + wl + j];
      const float w = gw.w[j];
      const float sq = fmaf(b, b, a * a);   // x^2 + y^2
      const float ab = a * b;               // x*y
      h0 = fmaf(w, a,  h0);
      h1 = fmaf(w, b,  h1);
      h2 = fmaf(w, sq, h2);
      h3 = fmaf(w, ab, h3);
    }

    // shift-fma vertical accumulate: A[k] = w[10-k]*h + A[k+1] (in place,
    // ascending k reads old A[k+1] before overwrite); A[10] = w[0]*h.
    #pragma unroll
    for (int k = 0; k < 10; ++k) {
      A[0][k] = fmaf(gw.w[10 - k], h0, A[0][k + 1]);
      A[1][k] = fmaf(gw.w[10 - k], h1, A[1][k + 1]);
      A[2][k] = fmaf(gw.w[10 - k], h2, A[2][k + 1]);
      A[3][k] = fmaf(gw.w[10 - k], h3, A[3][k + 1]);
    }
    A[0][10] = gw.w[0] * h0;
    A[1][10] = gw.w[0] * h1;
    A[2][10] = gw.w[0] * h2;
    A[3][10] = gw.w[0] * h3;

    // output row i-10 complete in A[..][0] -> SSIM + sum
    if (i >= 10) {
      const float mu1 = A[0][0], mu2 = A[1][0];
      const float s3  = A[2][0], s4  = A[3][0];
      const float mu1s = mu1 * mu1, mu2s = mu2 * mu2, m12 = mu1 * mu2;
      const float num = (2.f * m12 + C1) * (2.f * (s4 - m12) + C2);
      const float den = (mu1s + mu2s + C1) * ((s3 - mu1s - mu2s) + C2);
      sum += num * __builtin_amdgcn_rcpf(den);
    }
  }

  // ---- block reduction (single barrier, end of kernel) ----
  #pragma unroll
  for (int off = 32; off > 0; off >>= 1) sum += __shfl_down(sum, off);
  __shared__ float wsum[NWV];
  if (lane == 0) wsum[wv] = sum;
  __syncthreads();
  if (tid == 0)
    partial[by * GX + bx] = wsum[0] + wsum[1];
}

__global__ __launch_bounds__(256) void ssim_reduce_kernel(
    const float* __restrict__ partial, float* __restrict__ out) {
  int tid = threadIdx.x;
  // 2048 partials (GX*GY)
  double s = 0.0;
  #pragma unroll
  for (int k = 0; k < 8; ++k) s += (double)partial[tid + 256 * k];
  #pragma unroll
  for (int off = 32; off > 0; off >>= 1) s += __shfl_down(s, off);
  __shared__ double ws[4];
  if ((tid & 63) == 0) ws[tid >> 6] = s;
  __syncthreads();
  if (tid == 0)
    out[0] = (float)((ws[0] + ws[1] + ws[2] + ws[3]) /
                     ((double)IMG_H * (double)IMG_W));
}

extern "C" void kernel_launch(void* const* d_in, const int* in_sizes, int n_in,
                              void* d_out, int out_size, void* d_ws, size_t ws_size,
                              hipStream_t stream) {
  const float* img1 = (const float*)d_in[0];
  const float* img2 = (const float*)d_in[1];
  float* partial = (float*)d_ws;
  float* out = (float*)d_out;

  GW gw;
  double g[11], s = 0.0;
  for (int i = 0; i < 11; ++i) {
    double x = i - 5.0;
    g[i] = exp(-(x * x) / (2.0 * 1.5 * 1.5));
    s += g[i];
  }
  for (int i = 0; i < 11; ++i) gw.w[i] = (float)(g[i] / s);

  dim3 grid(GX, GY);
  ssim_sweep_kernel<<<grid, 128, 0, stream>>>(img1, img2, partial, gw);
  ssim_reduce_kernel<<<1, 256, 0, stream>>>(partial, out);
}

// Round 9
// 180.936 us; speedup vs baseline: 1.1166x; 1.0261x over previous
//
#include <hip/hip_runtime.h>
#include <cmath>

#define IMG_H 4096
#define IMG_W 4096
#define GX 32
#define GY 64
#define TCOLS 128            /* output cols per block (2 waves x 64) */
#define WCOLS 64             /* output cols per wave (1 col per lane) */
#define R 64                 /* output rows per block */
#define NITER (R + 10)       /* 74 h-rows per strip */
#define NDIT (NITER / 2)     /* 37 double-iterations */
#define SW 80                /* staged words per img per row per wave */
#define RWORDS (2*SW)        /* 160 words per wave-row (img1 then img2) */
#define NBUF 4               /* LDS ring depth (rows i..i+3) */
#define NWV 2                /* waves per block */

struct GW { float w[11]; };

__device__ __forceinline__ int clampi(int v, int lo, int hi) {
  return v < lo ? lo : (v > hi ? hi : v);
}

// Round 9: double-row iterations (2 output rows / iter / lane).
// Round-8 post-mortem: grid fill did NOT move occupancy (30->32.5%); with
// VGPR_Count=40 but A[44] likely in AGPRs (unified file), true usage ~84
// regs -> 3 waves/SIMD cap. Reg-bound, not grid-bound. Calibration r5/r7/r8:
// ~305 VALU-issue instr-equiv per wave-iter vs ~150 body arithmetic -> ~half
// is per-iteration overhead (addressing, ring, patch, loop) and issue
// inflation. Lever: amortize it. Fused double absorb
//   o0 = fma(w10,h0,A[1]);  A[k] = fma(w[10-k],h1, fma(w[9-k],h0, A[k+2]))
//   A[9] = fma(w1,h1, w0*h0); A[10] = w0*h1; o1 = A[0]
// keeps 11 fma/row but halves iterations: overhead/row -25%, 2 independent
// h-conv chains double ILP. NBUF=4, prefetch i+2,i+3, vmcnt(2) (~1800 cy
// slack > 900 cy HBM). launch_bounds(128,3): cap 85, A+h+misc ~60-70.
// Lessons kept: wave-private LDS, no main-loop barriers (r2), w=16
// global_load_lds ring + counted vmcnt (r4/r7), rolled loop + shift
// register (r5), 1 col/lane (r7), 4-channel algebra.
__global__ __launch_bounds__(128, 3) void ssim_sweep_kernel(
    const float* __restrict__ img1, const float* __restrict__ img2,
    float* __restrict__ partial, GW gw) {
  __shared__ __align__(16) float sbuf[NWV][NBUF][RWORDS];  // 5120 B

  const int tid  = threadIdx.x;
  const int wv   = tid >> 6;
  const int lane = tid & 63;
  const int bx = blockIdx.x, by = blockIdx.y;
  const int cw   = bx * TCOLS + wv * WCOLS;   // this wave's first output col
  const int row0 = by * R;
  const bool ledge = (cw == 0), redge = (cw + WCOLS == IMG_W);

  // DMA map: one call, lanes 0..39 active; HW writes LDS base + 16*laneid.
  // lanes 0..19  -> img1 words 0..79   (cols [cw-8, cw+72))
  // lanes 20..39 -> img2 words 80..159
  const float* srcp = (lane < 20) ? img1 : img2;
  const int    co   = clampi(cw - 8 + 4 * ((lane < 20) ? lane : lane - 20),
                             0, IMG_W - 4);   // 16B-aligned (cw%64==0)

  float* swv = &sbuf[wv][0][0];

  auto stage = [&](int slot, int i) {
    const int gr = clampi(row0 - 5 + i, 0, IMG_H - 1);
    const long rb = (long)gr * IMG_W;
    float* dst = swv + slot * RWORDS;
    if (lane < 40) {
      __builtin_amdgcn_global_load_lds(
          (const __attribute__((address_space(1))) void*)(srcp + rb + co),
          (__attribute__((address_space(3))) void*)dst, 16, 0, 0);
    }
  };

  // ---- prologue: rows 0,1 in flight ----
  stage(0, 0);
  stage(1, 1);

  // shift-register accumulator: A[ch][k], k=0..10; 1 col per lane.
  float A[4][11];
  float sum = 0.f;
  const float C1 = 6.5025f, C2 = 58.5225f;
  const int wl = lane + 3;   // first window word (col cw+lane, taps -5..+5)

  #pragma unroll 1
  for (int t = 0; t < NDIT; ++t) {
    const int i = 2 * t;
    const int s0 = i & 3, s1 = (i + 1) & 3, s2 = (i + 2) & 3, s3 = (i + 3) & 3;

    // issue rows i+2, i+3 into the slots consumed at iter t-1
    // (tail: clamped re-reads into dead slots -- harmless, branch-free)
    stage(s2, i + 2);
    stage(s3, i + 3);

    // counted wait: the 2 just-issued ops stay in flight; rows i,i+1 landed
    asm volatile("s_waitcnt vmcnt(2)" ::: "memory");
    __builtin_amdgcn_sched_barrier(0);

    float* buf0 = swv + s0 * RWORDS;
    float* buf1 = swv + s1 * RWORDS;

    // replicate-pad patch (edge waves only): 32 lanes patch both buffers
    if (ledge || redge) {
      if (lane < 32) {
        const int bsel = lane >> 4;          // 0: buf0, 1: buf1
        const int im   = (lane >> 3) & 1;    // image half
        const int l    = lane & 7;
        float* bp = bsel ? buf1 : buf0;
        const int srcw = im * SW + (ledge ? 8 : 71);
        const int dstw = im * SW + (ledge ? l : 72 + l);
        bp[dstw] = bp[srcw];
      }
    }

    // fused 4-channel horizontal conv, both rows (independent chains)
    float h00 = 0.f, h01 = 0.f, h02 = 0.f, h03 = 0.f;
    float h10 = 0.f, h11 = 0.f, h12 = 0.f, h13 = 0.f;
    #pragma unroll
    for (int j = 0; j <= 10; ++j) {
      const float w = gw.w[j];
      {
        const float a = buf0[wl + j];
        const float b = buf0[SW + wl + j];
        const float sq = fmaf(b, b, a * a);
        const float ab = a * b;
        h00 = fmaf(w, a,  h00);
        h01 = fmaf(w, b,  h01);
        h02 = fmaf(w, sq, h02);
        h03 = fmaf(w, ab, h03);
      }
      {
        const float a = buf1[wl + j];
        const float b = buf1[SW + wl + j];
        const float sq = fmaf(b, b, a * a);
        const float ab = a * b;
        h10 = fmaf(w, a,  h10);
        h11 = fmaf(w, b,  h11);
        h12 = fmaf(w, sq, h12);
        h13 = fmaf(w, ab, h13);
      }
    }
    const float h0[4] = {h00, h01, h02, h03};
    const float h1[4] = {h10, h11, h12, h13};

    // fused double shift: absorb rows i and i+1, emit rows i-10 and i-9.
    // o0 = w10*h0 + A[1] (row i-10); after update, A[0] = row i-9.
    float o0[4], o1[4];
    #pragma unroll
    for (int ch = 0; ch < 4; ++ch) {
      o0[ch] = fmaf(gw.w[10], h0[ch], A[ch][1]);
      #pragma unroll
      for (int k = 0; k < 9; ++k)   // ascending: reads A[k+2] before write
        A[ch][k] = fmaf(gw.w[10 - k], h1[ch],
                        fmaf(gw.w[9 - k], h0[ch], A[ch][k + 2]));
      A[ch][9]  = fmaf(gw.w[1], h1[ch], gw.w[0] * h0[ch]);
      A[ch][10] = gw.w[0] * h1[ch];
      o1[ch] = A[ch][0];
    }

    // rows i-10, i-9 -> SSIM + sum (valid from i>=10, i.e. t>=5)
    if (i >= 10) {
      {
        const float mu1 = o0[0], mu2 = o0[1], s3v = o0[2], s4v = o0[3];
        const float mu1s = mu1 * mu1, mu2s = mu2 * mu2, m12 = mu1 * mu2;
        const float num = (2.f * m12 + C1) * (2.f * (s4v - m12) + C2);
        const float den = (mu1s + mu2s + C1) * ((s3v - mu1s - mu2s) + C2);
        sum += num * __builtin_amdgcn_rcpf(den);
      }
      {
        const float mu1 = o1[0], mu2 = o1[1], s3v = o1[2], s4v = o1[3];
        const float mu1s = mu1 * mu1, mu2s = mu2 * mu2, m12 = mu1 * mu2;
        const float num = (2.f * m12 + C1) * (2.f * (s4v - m12) + C2);
        const float den = (mu1s + mu2s + C1) * ((s3v - mu1s - mu2s) + C2);
        sum += num * __builtin_amdgcn_rcpf(den);
      }
    }
  }

  // ---- block reduction (single barrier, end of kernel) ----
  #pragma unroll
  for (int off = 32; off > 0; off >>= 1) sum += __shfl_down(sum, off);
  __shared__ float wsum[NWV];
  if (lane == 0) wsum[wv] = sum;
  __syncthreads();
  if (tid == 0)
    partial[by * GX + bx] = wsum[0] + wsum[1];
}

__global__ __launch_bounds__(256) void ssim_reduce_kernel(
    const float* __restrict__ partial, float* __restrict__ out) {
  int tid = threadIdx.x;
  // 2048 partials (GX*GY)
  double s = 0.0;
  #pragma unroll
  for (int k = 0; k < 8; ++k) s += (double)partial[tid + 256 * k];
  #pragma unroll
  for (int off = 32; off > 0; off >>= 1) s += __shfl_down(s, off);
  __shared__ double ws[4];
  if ((tid & 63) == 0) ws[tid >> 6] = s;
  __syncthreads();
  if (tid == 0)
    out[0] = (float)((ws[0] + ws[1] + ws[2] + ws[3]) /
                     ((double)IMG_H * (double)IMG_W));
}

extern "C" void kernel_launch(void* const* d_in, const int* in_sizes, int n_in,
                              void* d_out, int out_size, void* d_ws, size_t ws_size,
                              hipStream_t stream) {
  const float* img1 = (const float*)d_in[0];
  const float* img2 = (const float*)d_in[1];
  float* partial = (float*)d_ws;
  float* out = (float*)d_out;

  GW gw;
  double g[11], s = 0.0;
  for (int i = 0; i < 11; ++i) {
    double x = i - 5.0;
    g[i] = exp(-(x * x) / (2.0 * 1.5 * 1.5));
    s += g[i];
  }
  for (int i = 0; i < 11; ++i) gw.w[i] = (float)(g[i] / s);

  dim3 grid(GX, GY);
  ssim_sweep_kernel<<<grid, 128, 0, stream>>>(img1, img2, partial, gw);
  ssim_reduce_kernel<<<1, 256, 0, stream>>>(partial, out);
}